// Round 1
// baseline (610.117 us; speedup 1.0000x reference)
//
#include <hip/hip_runtime.h>
#include <hip/hip_bf16.h>

// Problem constants
#define BB 2
#define SS 2048
#define DD 1024
#define HH 16
#define DHH 64
// M = B*S = 4096 rows for all [*,1024] GEMMs

typedef __attribute__((ext_vector_type(8))) short bf16x8;
typedef __attribute__((ext_vector_type(4))) float f32x4;

__device__ __forceinline__ short f2bf(float f) {
    union { float f; unsigned u; } v; v.f = f;
    unsigned r = (v.u + 0x7FFFu + ((v.u >> 16) & 1u)) >> 16;
    return (short)r;
}

// ---------------------------------------------------------------------------
// Transpose + convert weight: W [1024][1024] f32 (in,out) -> WT [1024][1024] bf16 (out,in)
__global__ __launch_bounds__(256) void k_wt(const float* __restrict__ W, short* __restrict__ WT) {
    __shared__ float t[32][33];
    const int rb = blockIdx.y * 32, cb = blockIdx.x * 32;
    const int tr = threadIdx.x >> 3, tc = (threadIdx.x & 7) * 4;
    const float4 v = *reinterpret_cast<const float4*>(&W[(long)(rb + tr) * 1024 + cb + tc]);
    t[tr][tc + 0] = v.x; t[tr][tc + 1] = v.y; t[tr][tc + 2] = v.z; t[tr][tc + 3] = v.w;
    __syncthreads();
    short4 o;
    o.x = f2bf(t[tc + 0][tr]); o.y = f2bf(t[tc + 1][tr]);
    o.z = f2bf(t[tc + 2][tr]); o.w = f2bf(t[tc + 3][tr]);
    *reinterpret_cast<short4*>(&WT[(long)(cb + tr) * 1024 + rb + tc]) = o;
}

// ---------------------------------------------------------------------------
// Pack int32 mask (nonzero = masked) into bitmask words: bits[b][i][j/32]
__global__ __launch_bounds__(256) void k_mask_bits(const int* __restrict__ mask, unsigned* __restrict__ bits) {
    __shared__ int sm[8192];
    const long base = (long)blockIdx.x * 8192;
    const int tid = threadIdx.x;
#pragma unroll
    for (int i = 0; i < 8; ++i) {
        *reinterpret_cast<int4*>(&sm[i * 1024 + tid * 4]) =
            *reinterpret_cast<const int4*>(&mask[base + i * 1024 + tid * 4]);
    }
    __syncthreads();
    unsigned wv = 0;
#pragma unroll
    for (int j = 0; j < 32; ++j) wv |= (sm[tid * 32 + j] != 0 ? 1u : 0u) << j;
    bits[base / 32 + tid] = wv;
}

// ---------------------------------------------------------------------------
// GEMM: C = A[4096x1024](f32) * BT^T (BT is [N=1024][K=1024] bf16) + bias
// MODE 0: out bf16 at [b][h][s][dh]   (qh/kh layout)
// MODE 1: out bf16 at [b][h][dh][s]   (v transposed layout)
// MODE 2: out f32 = acc + bias + resid (x for LayerNorm), [4096][1024]
template<int MODE>
__global__ __launch_bounds__(256) void k_gemm(
    const float* __restrict__ A, const short* __restrict__ BT,
    const float* __restrict__ bias, const float* __restrict__ resid,
    void* __restrict__ outp)
{
    __shared__ short As[128][72];
    __shared__ short Bs[128][72];
    const int tid = threadIdx.x;
    const int rowbase = blockIdx.y * 128;
    const int colbase = blockIdx.x * 128;
    const int lane = tid & 63, w = tid >> 6;
    const int wr = (w >> 1) * 64, wc = (w & 1) * 64;
    const int lr = lane & 15, lg = lane >> 4;

    f32x4 acc[4][4] = {};

    for (int kb = 0; kb < 1024; kb += 64) {
        const int r0 = tid >> 3, c8 = (tid & 7) * 8;
#pragma unroll
        for (int p = 0; p < 4; ++p) {
            const int r = r0 + p * 32;
            const float* ap = A + (long)(rowbase + r) * 1024 + kb + c8;
            float4 f0 = *reinterpret_cast<const float4*>(ap);
            float4 f1 = *reinterpret_cast<const float4*>(ap + 4);
            bf16x8 av;
            av[0] = f2bf(f0.x); av[1] = f2bf(f0.y); av[2] = f2bf(f0.z); av[3] = f2bf(f0.w);
            av[4] = f2bf(f1.x); av[5] = f2bf(f1.y); av[6] = f2bf(f1.z); av[7] = f2bf(f1.w);
            *reinterpret_cast<bf16x8*>(&As[r][c8]) = av;
            *reinterpret_cast<bf16x8*>(&Bs[r][c8]) =
                *reinterpret_cast<const bf16x8*>(&BT[(long)(colbase + r) * 1024 + kb + c8]);
        }
        __syncthreads();
#pragma unroll
        for (int ks = 0; ks < 2; ++ks) {
            bf16x8 a[4], bfr[4];
#pragma unroll
            for (int m = 0; m < 4; ++m)
                a[m] = *reinterpret_cast<const bf16x8*>(&As[wr + m * 16 + lr][ks * 32 + lg * 8]);
#pragma unroll
            for (int n = 0; n < 4; ++n)
                bfr[n] = *reinterpret_cast<const bf16x8*>(&Bs[wc + n * 16 + lr][ks * 32 + lg * 8]);
#pragma unroll
            for (int m = 0; m < 4; ++m)
#pragma unroll
                for (int n = 0; n < 4; ++n)
                    acc[m][n] = __builtin_amdgcn_mfma_f32_16x16x32_bf16(a[m], bfr[n], acc[m][n], 0, 0, 0);
        }
        __syncthreads();
    }

#pragma unroll
    for (int m = 0; m < 4; ++m) {
#pragma unroll
        for (int n = 0; n < 4; ++n) {
            const int C = colbase + wc + n * 16 + lr;
            const float bv = bias[C];
#pragma unroll
            for (int rr = 0; rr < 4; ++rr) {
                const int R = rowbase + wr + m * 16 + lg * 4 + rr;
                float val = acc[m][n][rr] + bv;
                if (MODE == 0) {
                    const int b = R >> 11, s = R & 2047, h = C >> 6, dh = C & 63;
                    ((short*)outp)[(((long)(b * 16 + h) * 2048 + s) << 6) + dh] = f2bf(val);
                } else if (MODE == 1) {
                    const int b = R >> 11, s = R & 2047, h = C >> 6, dh = C & 63;
                    ((short*)outp)[(((long)(b * 16 + h) * 64 + dh) << 11) + s] = f2bf(val);
                } else {
                    const long idx = (long)R * 1024 + C;
                    ((float*)outp)[idx] = val + resid[idx];
                }
            }
        }
    }
}

// ---------------------------------------------------------------------------
// Attention: per wave = 16 q-rows of one (b,h). Two-pass masked softmax.
// qh/kh: [B,H,S,64] bf16 ; vt: [B,H,64,S] bf16 ; attn_out: [B,H,S,S] f32 ; ctx f32 [B,H,S,64]
__global__ __launch_bounds__(256) void k_attn(
    const short* __restrict__ qh, const short* __restrict__ kh,
    const short* __restrict__ vt, const unsigned* __restrict__ mbits,
    float* __restrict__ attn_out, float* __restrict__ ctx)
{
    const int bh = blockIdx.y, b = bh >> 4;
    const int tid = threadIdx.x;
    const int w = tid >> 6, lane = tid & 63;
    const int lr = lane & 15, lg = lane >> 4;
    const int ibase = blockIdx.x * 64 + w * 16;

    __shared__ short Pl[4][16][40];

    const short* qhp = qh + ((long)bh * 2048 + ibase) * 64;
    const short* khp = kh + (long)bh * 2048 * 64;
    const short* vtp = vt + (long)bh * 64 * 2048;
    const unsigned* mbp = mbits + (long)b * 2048 * 64 + (long)ibase * 64;

    const bf16x8 aq0 = *reinterpret_cast<const bf16x8*>(&qhp[lr * 64 + lg * 8]);
    const bf16x8 aq1 = *reinterpret_cast<const bf16x8*>(&qhp[lr * 64 + 32 + lg * 8]);

    auto tile_scores = [&](int jb) -> f32x4 {
        bf16x8 b0 = *reinterpret_cast<const bf16x8*>(&khp[(long)(jb + lr) * 64 + lg * 8]);
        bf16x8 b1 = *reinterpret_cast<const bf16x8*>(&khp[(long)(jb + lr) * 64 + 32 + lg * 8]);
        f32x4 sc = {};
        sc = __builtin_amdgcn_mfma_f32_16x16x32_bf16(aq0, b0, sc, 0, 0, 0);
        sc = __builtin_amdgcn_mfma_f32_16x16x32_bf16(aq1, b1, sc, 0, 0, 0);
        f32x4 out;
#pragma unroll
        for (int rr = 0; rr < 4; ++rr) {
            const unsigned mw = mbp[(lg * 4 + rr) * 64 + (jb >> 5)];
            const bool masked = (mw >> ((jb & 16) + lr)) & 1;
            out[rr] = masked ? -1e9f : sc[rr] * 0.125f;
        }
        return out;
    };

    // pass 1: per-lane online max / sum-of-exp (each lane owns cols j === lr (mod 16))
    float ml[4], ll[4];
#pragma unroll
    for (int rr = 0; rr < 4; ++rr) { ml[rr] = -1e30f; ll[rr] = 0.f; }

    for (int jb = 0; jb < 2048; jb += 16) {
        f32x4 s = tile_scores(jb);
#pragma unroll
        for (int rr = 0; rr < 4; ++rr) {
            const float mn = fmaxf(ml[rr], s[rr]);
            ll[rr] = ll[rr] * __expf(ml[rr] - mn) + __expf(s[rr] - mn);
            ml[rr] = mn;
        }
    }
    // cross-lane (16 lanes share a row-group) final reduce
    float mf[4], il[4];
#pragma unroll
    for (int rr = 0; rr < 4; ++rr) {
        float mx = ml[rr];
#pragma unroll
        for (int off = 1; off < 16; off <<= 1) mx = fmaxf(mx, __shfl_xor(mx, off, 16));
        float lw = ll[rr] * __expf(ml[rr] - mx);
#pragma unroll
        for (int off = 1; off < 16; off <<= 1) lw += __shfl_xor(lw, off, 16);
        mf[rr] = mx; il[rr] = 1.0f / lw;
    }

    // pass 2: recompute scores, write normalized attn, accumulate PV
    f32x4 accc[4] = {};
    for (int jb2 = 0; jb2 < 2048; jb2 += 32) {
#pragma unroll
        for (int half = 0; half < 2; ++half) {
            const int jb = jb2 + half * 16;
            f32x4 s = tile_scores(jb);
#pragma unroll
            for (int rr = 0; rr < 4; ++rr) {
                const float p = __expf(s[rr] - mf[rr]) * il[rr];
                const int i = ibase + lg * 4 + rr;
                attn_out[((long)bh * 2048 + i) * 2048 + jb + lr] = p;
                Pl[w][lg * 4 + rr][half * 16 + lr] = f2bf(p);
            }
        }
        __syncthreads();
        const bf16x8 ap = *reinterpret_cast<const bf16x8*>(&Pl[w][lr][lg * 8]);
#pragma unroll
        for (int g = 0; g < 4; ++g) {
            const bf16x8 bv = *reinterpret_cast<const bf16x8*>(&vtp[(long)(g * 16 + lr) * 2048 + jb2 + lg * 8]);
            accc[g] = __builtin_amdgcn_mfma_f32_16x16x32_bf16(ap, bv, accc[g], 0, 0, 0);
        }
        __syncthreads();
    }
#pragma unroll
    for (int g = 0; g < 4; ++g)
#pragma unroll
        for (int rr = 0; rr < 4; ++rr) {
            const int i = ibase + lg * 4 + rr;
            ctx[((long)bh * 2048 + i) * 64 + g * 16 + lr] = accc[g][rr];
        }
}

// ---------------------------------------------------------------------------
// LayerNorm over rows of x [4096][1024] f32
__global__ __launch_bounds__(256) void k_ln(const float* __restrict__ x,
    const float* __restrict__ gamma, const float* __restrict__ beta,
    float* __restrict__ out)
{
    __shared__ float red[8];
    const int r = blockIdx.x, tid = threadIdx.x;
    const float4 v = reinterpret_cast<const float4*>(x + (long)r * 1024)[tid];
    float s = v.x + v.y + v.z + v.w;
    float q2 = v.x * v.x + v.y * v.y + v.z * v.z + v.w * v.w;
#pragma unroll
    for (int off = 32; off; off >>= 1) {
        s += __shfl_xor(s, off, 64);
        q2 += __shfl_xor(q2, off, 64);
    }
    if ((tid & 63) == 0) { red[(tid >> 6) * 2] = s; red[(tid >> 6) * 2 + 1] = q2; }
    __syncthreads();
    s = red[0] + red[2] + red[4] + red[6];
    q2 = red[1] + red[3] + red[5] + red[7];
    const float mu = s * (1.0f / 1024.0f);
    const float var = q2 * (1.0f / 1024.0f) - mu * mu;
    const float rs = rsqrtf(var + 1e-5f);
    const float4 g = reinterpret_cast<const float4*>(gamma)[tid];
    const float4 bb = reinterpret_cast<const float4*>(beta)[tid];
    float4 o;
    o.x = (v.x - mu) * rs * g.x + bb.x;
    o.y = (v.y - mu) * rs * g.y + bb.y;
    o.z = (v.z - mu) * rs * g.z + bb.z;
    o.w = (v.w - mu) * rs * g.w + bb.w;
    reinterpret_cast<float4*>(out + (long)r * 1024)[tid] = o;
}

// ---------------------------------------------------------------------------
extern "C" void kernel_launch(void* const* d_in, const int* in_sizes, int n_in,
                              void* d_out, int out_size, void* d_ws, size_t ws_size,
                              hipStream_t stream)
{
    const float* qin  = (const float*)d_in[0];
    const float* kin  = (const float*)d_in[1];
    const float* vin  = (const float*)d_in[2];
    const int*   mask = (const int*)d_in[3];
    const float* Wq = (const float*)d_in[4];
    const float* bq = (const float*)d_in[5];
    const float* Wk = (const float*)d_in[6];
    const float* bk = (const float*)d_in[7];
    const float* Wv = (const float*)d_in[8];
    const float* bv = (const float*)d_in[9];
    const float* Wo = (const float*)d_in[10];
    const float* bo = (const float*)d_in[11];
    const float* gamma = (const float*)d_in[12];
    const float* beta  = (const float*)d_in[13];

    char* ws = (char*)d_ws;
    short* WqT = (short*)(ws + (0ul << 20));   // 2 MB each
    short* WkT = (short*)(ws + (2ul << 20));
    short* WvT = (short*)(ws + (4ul << 20));
    short* WoT = (short*)(ws + (6ul << 20));
    short* qh  = (short*)(ws + (8ul << 20));   // 8 MB each
    short* khb = (short*)(ws + (16ul << 20));
    short* vt  = (short*)(ws + (24ul << 20));
    float* ctx = (float*)(ws + (32ul << 20));  // 16 MB
    float* xb  = (float*)(ws + (48ul << 20));  // 16 MB
    unsigned* mb = (unsigned*)(ws + (64ul << 20)); // 1 MB

    float* outLN = (float*)d_out;
    float* attnO = (float*)d_out + 4194304;

    const dim3 blk(256);
    k_wt<<<dim3(32, 32), blk, 0, stream>>>(Wq, WqT);
    k_wt<<<dim3(32, 32), blk, 0, stream>>>(Wk, WkT);
    k_wt<<<dim3(32, 32), blk, 0, stream>>>(Wv, WvT);
    k_wt<<<dim3(32, 32), blk, 0, stream>>>(Wo, WoT);
    k_mask_bits<<<dim3(1024), blk, 0, stream>>>(mask, mb);

    const dim3 gg(8, 32);
    k_gemm<0><<<gg, blk, 0, stream>>>(qin, WqT, bq, nullptr, qh);
    k_gemm<0><<<gg, blk, 0, stream>>>(kin, WkT, bk, nullptr, khb);
    k_gemm<1><<<gg, blk, 0, stream>>>(vin, WvT, bv, nullptr, vt);

    k_attn<<<dim3(32, 32), blk, 0, stream>>>(qh, khb, vt, mb, attnO, ctx);

    k_gemm<2><<<gg, blk, 0, stream>>>(ctx, WoT, bo, qin, xb);
    k_ln<<<dim3(4096), blk, 0, stream>>>(xb, gamma, beta, outLN);
}

// Round 2
// 365.558 us; speedup vs baseline: 1.6690x; 1.6690x over previous
//
#include <hip/hip_runtime.h>
#include <hip/hip_bf16.h>

typedef __attribute__((ext_vector_type(8))) short bf16x8;
typedef __attribute__((ext_vector_type(4))) float f32x4;

__device__ __forceinline__ short f2bf(float f) {
    union { float f; unsigned u; } v; v.f = f;
    unsigned r = (v.u + 0x7FFFu + ((v.u >> 16) & 1u)) >> 16;
    return (short)r;
}
__device__ __forceinline__ float bf2f(short s) {
    union { unsigned u; float f; } v; v.u = ((unsigned)(unsigned short)s) << 16;
    return v.f;
}
__device__ __forceinline__ void gll16(const void* g, void* l) {
    __builtin_amdgcn_global_load_lds(
        (const __attribute__((address_space(1))) unsigned int*)g,
        (__attribute__((address_space(3))) unsigned int*)l, 16, 0, 0);
}

// ---------------------------------------------------------------------------
// f32 -> bf16 convert (8 elems/thread, exact-size grid)
__global__ __launch_bounds__(256) void k_cvt(const float* __restrict__ in, short* __restrict__ out) {
    const long i = ((long)blockIdx.x * 256 + threadIdx.x) * 8;
    float4 f0 = *reinterpret_cast<const float4*>(&in[i]);
    float4 f1 = *reinterpret_cast<const float4*>(&in[i + 4]);
    bf16x8 v;
    v[0] = f2bf(f0.x); v[1] = f2bf(f0.y); v[2] = f2bf(f0.z); v[3] = f2bf(f0.w);
    v[4] = f2bf(f1.x); v[5] = f2bf(f1.y); v[6] = f2bf(f1.z); v[7] = f2bf(f1.w);
    *reinterpret_cast<bf16x8*>(&out[i]) = v;
}

// ---------------------------------------------------------------------------
// Transpose + convert weight: W [1024][1024] f32 (in,out) -> WT bf16 (out,in)
__global__ __launch_bounds__(256) void k_wt(const float* __restrict__ W, short* __restrict__ WT) {
    __shared__ float t[32][33];
    const int rb = blockIdx.y * 32, cb = blockIdx.x * 32;
    const int tr = threadIdx.x >> 3, tc = (threadIdx.x & 7) * 4;
    const float4 v = *reinterpret_cast<const float4*>(&W[(long)(rb + tr) * 1024 + cb + tc]);
    t[tr][tc + 0] = v.x; t[tr][tc + 1] = v.y; t[tr][tc + 2] = v.z; t[tr][tc + 3] = v.w;
    __syncthreads();
    short4 o;
    o.x = f2bf(t[tc + 0][tr]); o.y = f2bf(t[tc + 1][tr]);
    o.z = f2bf(t[tc + 2][tr]); o.w = f2bf(t[tc + 3][tr]);
    *reinterpret_cast<short4*>(&WT[(long)(cb + tr) * 1024 + rb + tc]) = o;
}

// ---------------------------------------------------------------------------
__global__ __launch_bounds__(256) void k_mask_bits(const int* __restrict__ mask, unsigned* __restrict__ bits) {
    __shared__ int sm[8192];
    const long base = (long)blockIdx.x * 8192;
    const int tid = threadIdx.x;
#pragma unroll
    for (int i = 0; i < 8; ++i) {
        *reinterpret_cast<int4*>(&sm[i * 1024 + tid * 4]) =
            *reinterpret_cast<const int4*>(&mask[base + i * 1024 + tid * 4]);
    }
    __syncthreads();
    unsigned wv = 0;
#pragma unroll
    for (int j = 0; j < 32; ++j) wv |= (sm[tid * 32 + j] != 0 ? 1u : 0u) << j;
    bits[base / 32 + tid] = wv;
}

// ---------------------------------------------------------------------------
// GEMM m97-style: A bf16 [4096][1024] row-major, BT bf16 [N][K]=[1024][1024].
// 128x128 tile, BK=64, global_load_lds w/ XOR-swizzled source chunks.
// MODE 0: out bf16 [b][h][s][dh] (scaled); MODE 1: bf16 [b][h][dh][s]; MODE 2: f32 + resid.
template<int MODE>
__global__ __launch_bounds__(256) void k_gemm2(
    const short* __restrict__ A, const short* __restrict__ BT,
    const float* __restrict__ bias, const float* __restrict__ resid,
    void* __restrict__ outp, float scale)
{
    __shared__ short As[128 * 64];
    __shared__ short Bs[128 * 64];
    const int tid = threadIdx.x, w = tid >> 6, lane = tid & 63;
    const int lr = lane & 15, lg = lane >> 4;
    const int rowbase = blockIdx.y * 128, colbase = blockIdx.x * 128;
    const int wr = (w >> 1) * 64, wc = (w & 1) * 64;
    const int srow = lane >> 3, sc_ = (lane & 7) ^ srow;

    f32x4 acc[4][4] = {};

    for (int kb = 0; kb < 1024; kb += 64) {
#pragma unroll
        for (int ii = 0; ii < 4; ++ii) {
            const int rl = w * 32 + ii * 8 + srow;
            gll16(A + (long)(rowbase + rl) * 1024 + kb + sc_ * 8, &As[(w * 32 + ii * 8) * 64]);
            gll16(BT + (long)(colbase + rl) * 1024 + kb + sc_ * 8, &Bs[(w * 32 + ii * 8) * 64]);
        }
        __syncthreads();
#pragma unroll
        for (int ks = 0; ks < 2; ++ks) {
            bf16x8 a[4], bq[4];
#pragma unroll
            for (int m = 0; m < 4; ++m) {
                const int r = wr + m * 16 + lr;
                a[m] = *reinterpret_cast<const bf16x8*>(&As[r * 64 + (((ks * 4 + lg) ^ (r & 7)) << 3)]);
            }
#pragma unroll
            for (int n = 0; n < 4; ++n) {
                const int r = wc + n * 16 + lr;
                bq[n] = *reinterpret_cast<const bf16x8*>(&Bs[r * 64 + (((ks * 4 + lg) ^ (r & 7)) << 3)]);
            }
#pragma unroll
            for (int m = 0; m < 4; ++m)
#pragma unroll
                for (int n = 0; n < 4; ++n)
                    acc[m][n] = __builtin_amdgcn_mfma_f32_16x16x32_bf16(a[m], bq[n], acc[m][n], 0, 0, 0);
        }
        __syncthreads();
    }

#pragma unroll
    for (int m = 0; m < 4; ++m) {
#pragma unroll
        for (int n = 0; n < 4; ++n) {
            const int C = colbase + wc + n * 16 + lr;
            const float bv = bias[C];
#pragma unroll
            for (int rr = 0; rr < 4; ++rr) {
                const int R = rowbase + wr + m * 16 + lg * 4 + rr;
                float val = (acc[m][n][rr] + bv) * scale;
                if (MODE == 0) {
                    const int b = R >> 11, s = R & 2047, h = C >> 6, dh = C & 63;
                    ((short*)outp)[(((long)(b * 16 + h) * 2048 + s) << 6) + dh] = f2bf(val);
                } else if (MODE == 1) {
                    const int b = R >> 11, s = R & 2047, h = C >> 6, dh = C & 63;
                    ((short*)outp)[(((long)(b * 16 + h) * 64 + dh) << 11) + s] = f2bf(val);
                } else {
                    const long idx = (long)R * 1024 + C;
                    ((float*)outp)[idx] = val + resid[idx];
                }
            }
        }
    }
}

// ---------------------------------------------------------------------------
// Attention. Per wave: 16 q rows. K/V tiles (64 rows x 64) LDS-staged per block.
// qh [B,H,S,64] bf16 (pre-scaled by 1/8); kh same (unscaled); vt [B,H,64,S] bf16.
__global__ __launch_bounds__(256) void k_attn(
    const short* __restrict__ qh, const short* __restrict__ kh,
    const short* __restrict__ vt, const unsigned* __restrict__ mbits,
    float* __restrict__ attn_out, short* __restrict__ ctxb)
{
    const int bh = blockIdx.y, b = bh >> 4;
    const int tid = threadIdx.x, w = tid >> 6, lane = tid & 63;
    const int lr = lane & 15, lg = lane >> 4;
    const int ibase = blockIdx.x * 64 + w * 16;

    __shared__ short Ks[64 * 64];
    __shared__ short Vs[64 * 64];
    __shared__ short Ps[4][16 * 72];

    const short* qhp = qh + ((long)bh * 2048 + ibase) * 64;
    const short* khp = kh + (long)bh * 2048 * 64;
    const short* vtp = vt + (long)bh * 64 * 2048;
    const unsigned* mbp = mbits + (long)b * 2048 * 64 + (long)ibase * 64;

    const bf16x8 aq0 = *reinterpret_cast<const bf16x8*>(&qhp[lr * 64 + lg * 8]);
    const bf16x8 aq1 = *reinterpret_cast<const bf16x8*>(&qhp[lr * 64 + 32 + lg * 8]);

    const int srow = lane >> 3, sc_ = (lane & 7) ^ srow;

    auto stage_k = [&](int ch) {
#pragma unroll
        for (int ii = 0; ii < 2; ++ii) {
            const int rl = w * 16 + ii * 8 + srow;
            gll16(khp + (long)(ch * 64 + rl) * 64 + sc_ * 8, &Ks[(w * 16 + ii * 8) * 64]);
        }
    };
    auto stage_v = [&](int ch) {
#pragma unroll
        for (int ii = 0; ii < 2; ++ii) {
            const int rl = w * 16 + ii * 8 + srow;
            gll16(vtp + (long)rl * 2048 + ch * 64 + sc_ * 8, &Vs[(w * 16 + ii * 8) * 64]);
        }
    };
    auto kfrag = [&](int t, int ks) -> bf16x8 {
        const int r = t * 16 + lr;
        return *reinterpret_cast<const bf16x8*>(&Ks[r * 64 + (((ks * 4 + lg) ^ (r & 7)) << 3)]);
    };
    auto vfrag = [&](int g, int ks) -> bf16x8 {
        const int r = g * 16 + lr;
        return *reinterpret_cast<const bf16x8*>(&Vs[r * 64 + (((ks * 4 + lg) ^ (r & 7)) << 3)]);
    };

    // ---------------- pass 1: online max/sum (1 exp per element) -------------
    float ml[4], ll[4];
#pragma unroll
    for (int rr = 0; rr < 4; ++rr) { ml[rr] = -3.0e38f; ll[rr] = 0.f; }

    for (int ch = 0; ch < 32; ++ch) {
        stage_k(ch);
        __syncthreads();
        unsigned mw[4][2];
#pragma unroll
        for (int rr = 0; rr < 4; ++rr)
#pragma unroll
            for (int h = 0; h < 2; ++h)
                mw[rr][h] = mbp[(lg * 4 + rr) * 64 + ch * 2 + h];
#pragma unroll
        for (int t = 0; t < 4; ++t) {
            f32x4 sc = {};
            sc = __builtin_amdgcn_mfma_f32_16x16x32_bf16(aq0, kfrag(t, 0), sc, 0, 0, 0);
            sc = __builtin_amdgcn_mfma_f32_16x16x32_bf16(aq1, kfrag(t, 1), sc, 0, 0, 0);
#pragma unroll
            for (int rr = 0; rr < 4; ++rr) {
                const bool masked = (mw[rr][t >> 1] >> (((t & 1) << 4) + lr)) & 1;
                const float s = masked ? -1e9f : sc[rr];
                const float d = s - ml[rr];
                const float e = __expf(-fabsf(d));
                const bool gt = d > 0.f;
                ll[rr] = gt ? ll[rr] * e + 1.f : ll[rr] + e;
                ml[rr] = gt ? s : ml[rr];
            }
        }
        __syncthreads();
    }

    float mf[4], il[4];
#pragma unroll
    for (int rr = 0; rr < 4; ++rr) {
        float mx = ml[rr];
#pragma unroll
        for (int off = 1; off < 16; off <<= 1) mx = fmaxf(mx, __shfl_xor(mx, off, 16));
        float lw = ll[rr] * __expf(ml[rr] - mx);
#pragma unroll
        for (int off = 1; off < 16; off <<= 1) lw += __shfl_xor(lw, off, 16);
        mf[rr] = mx; il[rr] = 1.0f / lw;
    }

    // ---------------- pass 2: recompute, write attn (coalesced), PV ----------
    f32x4 accc[4] = {};
    const long arow0 = (long)bh * 2048 + ibase;

    for (int ch = 0; ch < 32; ++ch) {
        stage_k(ch);
        stage_v(ch);
        __syncthreads();
        unsigned mw[4][2];
#pragma unroll
        for (int rr = 0; rr < 4; ++rr)
#pragma unroll
            for (int h = 0; h < 2; ++h)
                mw[rr][h] = mbp[(lg * 4 + rr) * 64 + ch * 2 + h];
#pragma unroll
        for (int t = 0; t < 4; ++t) {
            f32x4 sc = {};
            sc = __builtin_amdgcn_mfma_f32_16x16x32_bf16(aq0, kfrag(t, 0), sc, 0, 0, 0);
            sc = __builtin_amdgcn_mfma_f32_16x16x32_bf16(aq1, kfrag(t, 1), sc, 0, 0, 0);
#pragma unroll
            for (int rr = 0; rr < 4; ++rr) {
                const bool masked = (mw[rr][t >> 1] >> (((t & 1) << 4) + lr)) & 1;
                const float s = masked ? -1e9f : sc[rr];
                const float p = __expf(s - mf[rr]) * il[rr];
                Ps[w][(lg * 4 + rr) * 72 + t * 16 + lr] = f2bf(p);
            }
        }
        // PV from P-stage + V-stage
#pragma unroll
        for (int ks = 0; ks < 2; ++ks) {
            const bf16x8 pa = *reinterpret_cast<const bf16x8*>(&Ps[w][lr * 72 + ks * 32 + lg * 8]);
#pragma unroll
            for (int g = 0; g < 4; ++g)
                accc[g] = __builtin_amdgcn_mfma_f32_16x16x32_bf16(pa, vfrag(g, ks), accc[g], 0, 0, 0);
        }
        // coalesced attn writeout: 4 rows x 256B per instruction
#pragma unroll
        for (int i2 = 0; i2 < 4; ++i2) {
            const int r = i2 * 4 + lg;
            const short4 p4 = *reinterpret_cast<const short4*>(&Ps[w][r * 72 + lr * 4]);
            float4 o;
            o.x = bf2f(p4.x); o.y = bf2f(p4.y); o.z = bf2f(p4.z); o.w = bf2f(p4.w);
            *reinterpret_cast<float4*>(&attn_out[(arow0 + r) * 2048 + ch * 64 + lr * 4]) = o;
        }
        __syncthreads();
    }

#pragma unroll
    for (int g = 0; g < 4; ++g)
#pragma unroll
        for (int rr = 0; rr < 4; ++rr)
            ctxb[(arow0 + lg * 4 + rr) * 64 + g * 16 + lr] = f2bf(accc[g][rr]);
}

// ---------------------------------------------------------------------------
__global__ __launch_bounds__(256) void k_ln(const float* __restrict__ x,
    const float* __restrict__ gamma, const float* __restrict__ beta,
    float* __restrict__ out)
{
    __shared__ float red[8];
    const int r = blockIdx.x, tid = threadIdx.x;
    const float4 v = reinterpret_cast<const float4*>(x + (long)r * 1024)[tid];
    float s = v.x + v.y + v.z + v.w;
    float q2 = v.x * v.x + v.y * v.y + v.z * v.z + v.w * v.w;
#pragma unroll
    for (int off = 32; off; off >>= 1) {
        s += __shfl_xor(s, off, 64);
        q2 += __shfl_xor(q2, off, 64);
    }
    if ((tid & 63) == 0) { red[(tid >> 6) * 2] = s; red[(tid >> 6) * 2 + 1] = q2; }
    __syncthreads();
    s = red[0] + red[2] + red[4] + red[6];
    q2 = red[1] + red[3] + red[5] + red[7];
    const float mu = s * (1.0f / 1024.0f);
    const float var = q2 * (1.0f / 1024.0f) - mu * mu;
    const float rs = rsqrtf(var + 1e-5f);
    const float4 g = reinterpret_cast<const float4*>(gamma)[tid];
    const float4 bb = reinterpret_cast<const float4*>(beta)[tid];
    float4 o;
    o.x = (v.x - mu) * rs * g.x + bb.x;
    o.y = (v.y - mu) * rs * g.y + bb.y;
    o.z = (v.z - mu) * rs * g.z + bb.z;
    o.w = (v.w - mu) * rs * g.w + bb.w;
    reinterpret_cast<float4*>(out + (long)r * 1024)[tid] = o;
}

// ---------------------------------------------------------------------------
extern "C" void kernel_launch(void* const* d_in, const int* in_sizes, int n_in,
                              void* d_out, int out_size, void* d_ws, size_t ws_size,
                              hipStream_t stream)
{
    const float* qin  = (const float*)d_in[0];
    const float* kin  = (const float*)d_in[1];
    const float* vin  = (const float*)d_in[2];
    const int*   mask = (const int*)d_in[3];
    const float* Wq = (const float*)d_in[4];
    const float* bq = (const float*)d_in[5];
    const float* Wk = (const float*)d_in[6];
    const float* bk = (const float*)d_in[7];
    const float* Wv = (const float*)d_in[8];
    const float* bv = (const float*)d_in[9];
    const float* Wo = (const float*)d_in[10];
    const float* bo = (const float*)d_in[11];
    const float* gamma = (const float*)d_in[12];
    const float* beta  = (const float*)d_in[13];

    char* ws = (char*)d_ws;
    short* WqT = (short*)(ws + (0ul  << 20));
    short* WkT = (short*)(ws + (2ul  << 20));
    short* WvT = (short*)(ws + (4ul  << 20));
    short* WoT = (short*)(ws + (6ul  << 20));
    short* qbf = (short*)(ws + (8ul  << 20));   // dead after q-proj; reused by xb
    short* kbf = (short*)(ws + (16ul << 20));   // dead after k-proj; reused by xb
    short* vbf = (short*)(ws + (24ul << 20));
    short* qh  = (short*)(ws + (32ul << 20));
    short* khb = (short*)(ws + (40ul << 20));
    short* vtb = (short*)(ws + (48ul << 20));
    unsigned* mb = (unsigned*)(ws + (56ul << 20));
    short* ctxb = (short*)(ws + (57ul << 20));  // 8 MB
    float* xb   = (float*)(ws + (8ul  << 20));  // 16 MB, overlaps dead qbf/kbf

    float* outLN = (float*)d_out;
    float* attnO = (float*)d_out + 4194304;

    const dim3 blk(256);
    k_cvt<<<dim3(2048), blk, 0, stream>>>(qin, qbf);
    k_cvt<<<dim3(2048), blk, 0, stream>>>(kin, kbf);
    k_cvt<<<dim3(2048), blk, 0, stream>>>(vin, vbf);
    k_wt<<<dim3(32, 32), blk, 0, stream>>>(Wq, WqT);
    k_wt<<<dim3(32, 32), blk, 0, stream>>>(Wk, WkT);
    k_wt<<<dim3(32, 32), blk, 0, stream>>>(Wv, WvT);
    k_wt<<<dim3(32, 32), blk, 0, stream>>>(Wo, WoT);
    k_mask_bits<<<dim3(1024), blk, 0, stream>>>(mask, mb);

    const dim3 gg(8, 32);
    k_gemm2<0><<<gg, blk, 0, stream>>>(qbf, WqT, bq, nullptr, qh,  0.125f);
    k_gemm2<0><<<gg, blk, 0, stream>>>(kbf, WkT, bk, nullptr, khb, 1.0f);
    k_gemm2<1><<<gg, blk, 0, stream>>>(vbf, WvT, bv, nullptr, vtb, 1.0f);

    k_attn<<<dim3(32, 32), blk, 0, stream>>>(qh, khb, vtb, mb, attnO, ctxb);

    k_gemm2<2><<<gg, blk, 0, stream>>>(ctxb, WoT, bo, qin, xb, 1.0f);
    k_ln<<<dim3(4096), blk, 0, stream>>>(xb, gamma, beta, outLN);
}